// Round 4
// baseline (913.566 us; speedup 1.0000x reference)
//
#include <hip/hip_runtime.h>
#include <math.h>

// NNUE forward, all f32. B=8192, N_IN=12288, H0=256, H1=H2=32.
// R4: producer/consumer split.
//   Kernel A (scan): pure-bandwidth stream of white/black, emit per-sample
//     nonzero index lists to d_ws (global atomics on per-sample counters).
//   Kernel B (gather+MLP): per-sample block gathers ft_w^T columns (L3-resident)
//     and runs the tail layers.
// Floor: streaming 805 MB of feature data (~128 us at 6.3 TB/s).

#define NIN   12288
#define NF4   3072   // NIN / 4 floats per float4
#define FPT   12     // NF4 / 256 threads (fallback kernel)
#define H0    256
#define MAXF  192    // per-sample active-feature cap (mean ~31, 192 = +29 sigma)

// ---------------------------------------------------------------- transpose
// ft_w (256 x 12288) -> ft_w_T (12288 x 256), f32, LDS-tiled.
__global__ __launch_bounds__(256) void transpose_ftw(const float* __restrict__ src,
                                                     float* __restrict__ dst) {
    __shared__ float tile[32][33];
    const int jb = blockIdx.x * 32;
    const int hb = blockIdx.y * 32;
    const int tx = threadIdx.x;
    const int ty = threadIdx.y;
#pragma unroll
    for (int r = 0; r < 32; r += 8)
        tile[ty + r][tx] = src[(size_t)(hb + ty + r) * NIN + jb + tx];
    __syncthreads();
#pragma unroll
    for (int r = 0; r < 32; r += 8)
        dst[(size_t)(jb + ty + r) * H0 + hb + tx] = tile[tx][ty + r];
}

// ---------------------------------------------------------------- zero counts
__global__ __launch_bounds__(256) void zero_counts(int* __restrict__ cnts, int n) {
    const int i = blockIdx.x * 256 + threadIdx.x;
    if (i < n) cnts[i] = 0;
}

// ---------------------------------------------------------------- kernel A
__device__ __forceinline__ void scanv(uint4 u, int i,
                                      int* __restrict__ cnts,
                                      int* __restrict__ lists) {
    if (u.x | u.y | u.z | u.w) {          // ~1% taken
        const int s  = i / NF4;
        const int jb = (i - s * NF4) << 2;
        int* lst = lists + (size_t)s * MAXF;
        int* c   = cnts + s;
        if (u.x) { int p = atomicAdd(c, 1); if (p < MAXF) lst[p] = jb + 0; }
        if (u.y) { int p = atomicAdd(c, 1); if (p < MAXF) lst[p] = jb + 1; }
        if (u.z) { int p = atomicAdd(c, 1); if (p < MAXF) lst[p] = jb + 2; }
        if (u.w) { int p = atomicAdd(c, 1); if (p < MAXF) lst[p] = jb + 3; }
    }
}

__global__ __launch_bounds__(256) void scan_kernel(const uint4* __restrict__ white,
                                                   const uint4* __restrict__ black,
                                                   int* __restrict__ cnts,   // [2*B]
                                                   int* __restrict__ lists,  // [2*B*MAXF]
                                                   int total)                // B*NF4
{
    const int stride = gridDim.x * 256;
    int i = blockIdx.x * 256 + threadIdx.x;
    int* cnts_b  = cnts;            // white at [0,B), black at [B,2B) via +total offset trick
    // black uses sample id (B + s): pass via pointer offset below in caller-free way:
    // we compute it locally: black sample base = total/NF4.
    const int B = total / NF4;
    for (; i + 3 * stride < total; i += 4 * stride) {
        const uint4 w0 = white[i];
        const uint4 w1 = white[i + stride];
        const uint4 w2 = white[i + 2 * stride];
        const uint4 w3 = white[i + 3 * stride];
        const uint4 b0 = black[i];
        const uint4 b1 = black[i + stride];
        const uint4 b2 = black[i + 2 * stride];
        const uint4 b3 = black[i + 3 * stride];
        scanv(w0, i,              cnts_b, lists);
        scanv(w1, i + stride,     cnts_b, lists);
        scanv(w2, i + 2 * stride, cnts_b, lists);
        scanv(w3, i + 3 * stride, cnts_b, lists);
        scanv(b0, i + B * NF4,              cnts_b, lists);
        scanv(b1, i + stride + B * NF4,     cnts_b, lists);
        scanv(b2, i + 2 * stride + B * NF4, cnts_b, lists);
        scanv(b3, i + 3 * stride + B * NF4, cnts_b, lists);
    }
    for (; i < total; i += stride) {
        scanv(white[i], i, cnts_b, lists);
        scanv(black[i], i + B * NF4, cnts_b, lists);
    }
}

// ---------------------------------------------------------------- kernel B
__global__ __launch_bounds__(256) void gather_kernel(
    const int* __restrict__ side,        // (B,)
    const float* __restrict__ ftw,       // (NIN,256) transposed
    const float* __restrict__ ft_b,      // (256,)
    const float* __restrict__ l1_w,      // (32,512)
    const float* __restrict__ l1_b,
    const float* __restrict__ l2_w,      // (32,32)
    const float* __restrict__ l2_b,
    const float* __restrict__ l3_w,      // (32,)
    const float* __restrict__ l3_b,      // (1,)
    const int* __restrict__ cnts,        // [2*B]
    const int* __restrict__ lists,       // [2*B*MAXF]
    float* __restrict__ out,             // (B,)
    int B)
{
    __shared__ int w_list[MAXF];
    __shared__ int b_list[MAXF];
    __shared__ float sh_o0[512] __attribute__((aligned(16)));
    __shared__ float sh_o1[32];
    __shared__ float sh_o2[32];

    const int s   = blockIdx.x;
    const int tid = threadIdx.x;

    const int wn = min(cnts[s], MAXF);
    const int bn = min(cnts[B + s], MAXF);
    if (tid < wn) w_list[tid] = lists[(size_t)s * MAXF + tid];
    if (tid < bn) b_list[tid] = lists[(size_t)(B + s) * MAXF + tid];
    __syncthreads();

    // gather-sum ft_w^T columns; thread t owns hidden unit h=t; 8-wide ILP
    const float bias = ft_b[tid];
    const float* col = ftw + tid;
    float wacc = bias;
    float bacc = bias;
    {
        int k = 0;
        for (; k + 8 <= wn; k += 8) {
            const float f0 = col[(size_t)w_list[k]     * H0];
            const float f1 = col[(size_t)w_list[k + 1] * H0];
            const float f2 = col[(size_t)w_list[k + 2] * H0];
            const float f3 = col[(size_t)w_list[k + 3] * H0];
            const float f4 = col[(size_t)w_list[k + 4] * H0];
            const float f5 = col[(size_t)w_list[k + 5] * H0];
            const float f6 = col[(size_t)w_list[k + 6] * H0];
            const float f7 = col[(size_t)w_list[k + 7] * H0];
            wacc += ((f0 + f1) + (f2 + f3)) + ((f4 + f5) + (f6 + f7));
        }
        for (; k < wn; ++k) wacc += col[(size_t)w_list[k] * H0];
        k = 0;
        for (; k + 8 <= bn; k += 8) {
            const float f0 = col[(size_t)b_list[k]     * H0];
            const float f1 = col[(size_t)b_list[k + 1] * H0];
            const float f2 = col[(size_t)b_list[k + 2] * H0];
            const float f3 = col[(size_t)b_list[k + 3] * H0];
            const float f4 = col[(size_t)b_list[k + 4] * H0];
            const float f5 = col[(size_t)b_list[k + 5] * H0];
            const float f6 = col[(size_t)b_list[k + 6] * H0];
            const float f7 = col[(size_t)b_list[k + 7] * H0];
            bacc += ((f0 + f1) + (f2 + f3)) + ((f4 + f5) + (f6 + f7));
        }
        for (; k < bn; ++k) bacc += col[(size_t)b_list[k] * H0];
    }
    const float ow = fminf(fmaxf(wacc, 0.f), 1.f);
    const float ob = fminf(fmaxf(bacc, 0.f), 1.f);
    const bool sd = (side[s] != 0);
    sh_o0[tid]       = sd ? ow : ob;
    sh_o0[256 + tid] = sd ? ob : ow;
    __syncthreads();

    // l1: (32,512); 8 threads per output row, p-staggered (bank-conflict-free)
    {
        const int o = tid >> 3;
        const int p = tid & 7;
        const float4* wp = (const float4*)(l1_w + (o * 512 + p * 64));
        const float4* xp = (const float4*)(sh_o0 + p * 64);
        float sum = 0.f;
#pragma unroll
        for (int i = 0; i < 16; ++i) {
            const int v = (2 * p + i) & 15;
            float4 w4 = wp[v];
            float4 x4 = xp[v];
            sum += w4.x * x4.x + w4.y * x4.y + w4.z * x4.z + w4.w * x4.w;
        }
        sum += __shfl_down(sum, 4, 8);
        sum += __shfl_down(sum, 2, 8);
        sum += __shfl_down(sum, 1, 8);
        if (p == 0) sh_o1[o] = fminf(fmaxf(sum + l1_b[o], 0.f), 1.f);
    }
    __syncthreads();

    if (tid < 32) {
        float sum = 0.f;
#pragma unroll
        for (int k = 0; k < 32; ++k) sum += l2_w[tid * 32 + k] * sh_o1[k];
        sh_o2[tid] = fminf(fmaxf(sum + l2_b[tid], 0.f), 1.f);
    }
    __syncthreads();

    if (tid < 32) {
        float p = l3_w[tid] * sh_o2[tid];
        p += __shfl_down(p, 16, 32);
        p += __shfl_down(p, 8, 32);
        p += __shfl_down(p, 4, 32);
        p += __shfl_down(p, 2, 32);
        p += __shfl_down(p, 1, 32);
        if (tid == 0) {
            const float o3  = (p + l3_b[0]) * 300.0f;
            const float sig = 1.0f / (1.0f + expf(-o3 / 200.0f));
            out[s] = sig;
        }
    }
}

// ---------------------------------------------------------------- fallback (R3 monolith)
template <bool TRANSPOSED>
__global__ __launch_bounds__(256) void nnue_kernel(
    const float* __restrict__ white, const float* __restrict__ black,
    const int* __restrict__ side, const float* __restrict__ ftw,
    const float* __restrict__ ft_b, const float* __restrict__ l1_w,
    const float* __restrict__ l1_b, const float* __restrict__ l2_w,
    const float* __restrict__ l2_b, const float* __restrict__ l3_w,
    const float* __restrict__ l3_b, float* __restrict__ out)
{
    __shared__ int w_list[MAXF];
    __shared__ int b_list[MAXF];
    __shared__ int w_cnt, b_cnt;
    __shared__ float sh_o0[512] __attribute__((aligned(16)));
    __shared__ float sh_o1[32];
    __shared__ float sh_o2[32];
    const int s = blockIdx.x, tid = threadIdx.x;
    if (tid == 0) { w_cnt = 0; b_cnt = 0; }
    __syncthreads();
    const uint4* wrow = (const uint4*)(white + (size_t)s * NIN);
    const uint4* brow = (const uint4*)(black + (size_t)s * NIN);
#pragma unroll
    for (int i = 0; i < FPT; ++i) {
        const int v = i * 256 + tid;
        uint4 u = wrow[v];
        if (u.x | u.y | u.z | u.w) {
            if (u.x) { int p = atomicAdd(&w_cnt, 1); if (p < MAXF) w_list[p] = v * 4 + 0; }
            if (u.y) { int p = atomicAdd(&w_cnt, 1); if (p < MAXF) w_list[p] = v * 4 + 1; }
            if (u.z) { int p = atomicAdd(&w_cnt, 1); if (p < MAXF) w_list[p] = v * 4 + 2; }
            if (u.w) { int p = atomicAdd(&w_cnt, 1); if (p < MAXF) w_list[p] = v * 4 + 3; }
        }
        uint4 b = brow[v];
        if (b.x | b.y | b.z | b.w) {
            if (b.x) { int p = atomicAdd(&b_cnt, 1); if (p < MAXF) b_list[p] = v * 4 + 0; }
            if (b.y) { int p = atomicAdd(&b_cnt, 1); if (p < MAXF) b_list[p] = v * 4 + 1; }
            if (b.z) { int p = atomicAdd(&b_cnt, 1); if (p < MAXF) b_list[p] = v * 4 + 2; }
            if (b.w) { int p = atomicAdd(&b_cnt, 1); if (p < MAXF) b_list[p] = v * 4 + 3; }
        }
    }
    __syncthreads();
    const int wn = min(w_cnt, MAXF), bn = min(b_cnt, MAXF);
    const float bias = ft_b[tid];
    float wacc = bias, bacc = bias;
    for (int k = 0; k < wn; ++k) {
        const int j = w_list[k];
        wacc += TRANSPOSED ? ftw[(size_t)j * H0 + tid] : ftw[(size_t)tid * NIN + j];
    }
    for (int k = 0; k < bn; ++k) {
        const int j = b_list[k];
        bacc += TRANSPOSED ? ftw[(size_t)j * H0 + tid] : ftw[(size_t)tid * NIN + j];
    }
    const float ow = fminf(fmaxf(wacc, 0.f), 1.f);
    const float ob = fminf(fmaxf(bacc, 0.f), 1.f);
    const bool sd = (side[s] != 0);
    sh_o0[tid] = sd ? ow : ob;
    sh_o0[256 + tid] = sd ? ob : ow;
    __syncthreads();
    {
        const int o = tid >> 3, p = tid & 7;
        const float4* wp = (const float4*)(l1_w + (o * 512 + p * 64));
        const float4* xp = (const float4*)(sh_o0 + p * 64);
        float sum = 0.f;
#pragma unroll
        for (int i = 0; i < 16; ++i) {
            const int v = (2 * p + i) & 15;
            float4 w4 = wp[v]; float4 x4 = xp[v];
            sum += w4.x * x4.x + w4.y * x4.y + w4.z * x4.z + w4.w * x4.w;
        }
        sum += __shfl_down(sum, 4, 8);
        sum += __shfl_down(sum, 2, 8);
        sum += __shfl_down(sum, 1, 8);
        if (p == 0) sh_o1[o] = fminf(fmaxf(sum + l1_b[o], 0.f), 1.f);
    }
    __syncthreads();
    if (tid < 32) {
        float sum = 0.f;
#pragma unroll
        for (int k = 0; k < 32; ++k) sum += l2_w[tid * 32 + k] * sh_o1[k];
        sh_o2[tid] = fminf(fmaxf(sum + l2_b[tid], 0.f), 1.f);
    }
    __syncthreads();
    if (tid < 32) {
        float p = l3_w[tid] * sh_o2[tid];
        p += __shfl_down(p, 16, 32);
        p += __shfl_down(p, 8, 32);
        p += __shfl_down(p, 4, 32);
        p += __shfl_down(p, 2, 32);
        p += __shfl_down(p, 1, 32);
        if (tid == 0) {
            const float o3 = (p + l3_b[0]) * 300.0f;
            out[s] = 1.0f / (1.0f + expf(-o3 / 200.0f));
        }
    }
}

// ---------------------------------------------------------------- launch
extern "C" void kernel_launch(void* const* d_in, const int* in_sizes, int n_in,
                              void* d_out, int out_size, void* d_ws, size_t ws_size,
                              hipStream_t stream) {
    const float* white = (const float*)d_in[0];
    const float* black = (const float*)d_in[1];
    const int*   side  = (const int*)d_in[2];
    const float* ft_w  = (const float*)d_in[3];
    const float* ft_b  = (const float*)d_in[4];
    const float* l1_w  = (const float*)d_in[5];
    const float* l1_b  = (const float*)d_in[6];
    const float* l2_w  = (const float*)d_in[7];
    const float* l2_b  = (const float*)d_in[8];
    const float* l3_w  = (const float*)d_in[9];
    const float* l3_b  = (const float*)d_in[10];
    float*       out   = (float*)d_out;

    const int B = in_sizes[2];
    const size_t t_floats   = (size_t)NIN * H0;            // ftw_t
    const size_t cnt_ints   = (size_t)2 * B;               // counters
    const size_t list_ints  = (size_t)2 * B * MAXF;        // index lists
    const size_t need_bytes = t_floats * 4 + (cnt_ints + list_ints) * 4;

    if (ws_size >= need_bytes) {
        float* ftw_t = (float*)d_ws;
        int*   cnts  = (int*)((char*)d_ws + t_floats * 4);
        int*   lists = cnts + cnt_ints;
        const int total = B * NF4;

        hipLaunchKernelGGL(zero_counts, dim3((int)((cnt_ints + 255) / 256)), dim3(256),
                           0, stream, cnts, (int)cnt_ints);
        hipLaunchKernelGGL(transpose_ftw, dim3(NIN / 32, H0 / 32), dim3(32, 8), 0, stream,
                           ft_w, ftw_t);
        hipLaunchKernelGGL(scan_kernel, dim3(2048), dim3(256), 0, stream,
                           (const uint4*)white, (const uint4*)black, cnts, lists, total);
        hipLaunchKernelGGL(gather_kernel, dim3(B), dim3(256), 0, stream,
                           side, ftw_t, ft_b, l1_w, l1_b, l2_w, l2_b, l3_w, l3_b,
                           cnts, lists, out, B);
    } else if (ws_size >= t_floats * 4) {
        float* ftw_t = (float*)d_ws;
        hipLaunchKernelGGL(transpose_ftw, dim3(NIN / 32, H0 / 32), dim3(32, 8), 0, stream,
                           ft_w, ftw_t);
        hipLaunchKernelGGL((nnue_kernel<true>), dim3(B), dim3(256), 0, stream,
                           white, black, side, ftw_t, ft_b, l1_w, l1_b, l2_w, l2_b, l3_w, l3_b, out);
    } else {
        hipLaunchKernelGGL((nnue_kernel<false>), dim3(B), dim3(256), 0, stream,
                           white, black, side, ft_w, ft_b, l1_w, l1_b, l2_w, l2_b, l3_w, l3_b, out);
    }
}